// Round 1
// baseline (2231.070 us; speedup 1.0000x reference)
//
#include <hip/hip_runtime.h>

#define Bn 8
#define Vn 3
#define Hn 512
#define Wn 640
#define Nn (Hn * Wn)

// ---------- 4x4 helpers (row-major float[16]) ----------
// MESA-style cofactor inverse. Feeding row-major A into the column-major
// routine computes inv(A^T) in column-major == inv(A) in row-major.
__device__ __forceinline__ void mat4_inv(const float* m, float* o) {
    float inv[16];
    inv[0]  =  m[5]*m[10]*m[15] - m[5]*m[11]*m[14] - m[9]*m[6]*m[15] + m[9]*m[7]*m[14] + m[13]*m[6]*m[11] - m[13]*m[7]*m[10];
    inv[4]  = -m[4]*m[10]*m[15] + m[4]*m[11]*m[14] + m[8]*m[6]*m[15] - m[8]*m[7]*m[14] - m[12]*m[6]*m[11] + m[12]*m[7]*m[10];
    inv[8]  =  m[4]*m[9]*m[15]  - m[4]*m[11]*m[13] - m[8]*m[5]*m[15] + m[8]*m[7]*m[13] + m[12]*m[5]*m[11] - m[12]*m[7]*m[9];
    inv[12] = -m[4]*m[9]*m[14]  + m[4]*m[10]*m[13] + m[8]*m[5]*m[14] - m[8]*m[6]*m[13] - m[12]*m[5]*m[10] + m[12]*m[6]*m[9];
    inv[1]  = -m[1]*m[10]*m[15] + m[1]*m[11]*m[14] + m[9]*m[2]*m[15] - m[9]*m[3]*m[14] - m[13]*m[2]*m[11] + m[13]*m[3]*m[10];
    inv[5]  =  m[0]*m[10]*m[15] - m[0]*m[11]*m[14] - m[8]*m[2]*m[15] + m[8]*m[3]*m[14] + m[12]*m[2]*m[11] - m[12]*m[3]*m[10];
    inv[9]  = -m[0]*m[9]*m[15]  + m[0]*m[11]*m[13] + m[8]*m[1]*m[15] - m[8]*m[3]*m[13] - m[12]*m[1]*m[11] + m[12]*m[3]*m[9];
    inv[13] =  m[0]*m[9]*m[14]  - m[0]*m[10]*m[13] - m[8]*m[1]*m[14] + m[8]*m[2]*m[13] + m[12]*m[1]*m[10] - m[12]*m[2]*m[9];
    inv[2]  =  m[1]*m[6]*m[15]  - m[1]*m[7]*m[14]  - m[5]*m[2]*m[15] + m[5]*m[3]*m[14] + m[13]*m[2]*m[7]  - m[13]*m[3]*m[6];
    inv[6]  = -m[0]*m[6]*m[15]  + m[0]*m[7]*m[14]  + m[4]*m[2]*m[15] - m[4]*m[3]*m[14] - m[12]*m[2]*m[7]  + m[12]*m[3]*m[6];
    inv[10] =  m[0]*m[5]*m[15]  - m[0]*m[7]*m[13]  - m[4]*m[1]*m[15] + m[4]*m[3]*m[13] + m[12]*m[1]*m[7]  - m[12]*m[3]*m[5];
    inv[14] = -m[0]*m[5]*m[14]  + m[0]*m[6]*m[13]  + m[4]*m[1]*m[14] - m[4]*m[2]*m[13] - m[12]*m[1]*m[6]  + m[12]*m[2]*m[5];
    inv[3]  = -m[1]*m[6]*m[11]  + m[1]*m[7]*m[10]  + m[5]*m[2]*m[11] - m[5]*m[3]*m[10] - m[9]*m[2]*m[7]   + m[9]*m[3]*m[6];
    inv[7]  =  m[0]*m[6]*m[11]  - m[0]*m[7]*m[10]  - m[4]*m[2]*m[11] + m[4]*m[3]*m[10] + m[8]*m[2]*m[7]   - m[8]*m[3]*m[6];
    inv[11] = -m[0]*m[5]*m[11]  + m[0]*m[7]*m[9]   + m[4]*m[1]*m[11] - m[4]*m[3]*m[9]  - m[8]*m[1]*m[7]   + m[8]*m[3]*m[5];
    inv[15] =  m[0]*m[5]*m[10]  - m[0]*m[6]*m[9]   - m[4]*m[1]*m[10] + m[4]*m[2]*m[9]  + m[8]*m[1]*m[6]   - m[8]*m[2]*m[5];
    float det = m[0]*inv[0] + m[1]*inv[4] + m[2]*inv[8] + m[3]*inv[12];
    float rdet = 1.0f / det;
    for (int k = 0; k < 16; ++k) o[k] = inv[k] * rdet;
}

__device__ __forceinline__ void mat4_mul(const float* a, const float* b, float* c) {
    for (int r = 0; r < 4; ++r)
        for (int col = 0; col < 4; ++col) {
            float s = 0.0f;
            for (int k = 0; k < 4; ++k) s = fmaf(a[r*4 + k], b[k*4 + col], s);
            c[r*4 + col] = s;
        }
}

// ---------- Stage 1: P[b,i,j] = K[b] * RT[b,j] * inv(RT[b,i]) * inv(K[b]) ----------
__global__ void compute_P_kernel(const float* __restrict__ K,
                                 const float* __restrict__ RT,
                                 float* __restrict__ P) {
    int idx = blockIdx.x * blockDim.x + threadIdx.x;
    if (idx >= Bn * Vn * Vn) return;
    int b  = idx / (Vn * Vn);
    int ij = idx % (Vn * Vn);
    int i  = ij / Vn;
    int j  = ij % Vn;

    float Kb[16], Kinv[16], RTj[16], RTi[16], RTiinv[16], t1[16], t2[16], Pm[16];
    for (int k = 0; k < 16; ++k) Kb[k]  = K[b * 16 + k];
    for (int k = 0; k < 16; ++k) RTj[k] = RT[(b * Vn + j) * 16 + k];
    for (int k = 0; k < 16; ++k) RTi[k] = RT[(b * Vn + i) * 16 + k];
    mat4_inv(Kb, Kinv);
    mat4_inv(RTi, RTiinv);
    mat4_mul(Kb, RTj, t1);
    mat4_mul(t1, RTiinv, t2);
    mat4_mul(t2, Kinv, Pm);
    for (int k = 0; k < 16; ++k) P[idx * 16 + k] = Pm[k];
}

// ---------- Stage 2: per-pixel projection + bilinear sample + reduce ----------
__global__ __launch_bounds__(256) void loss_main_kernel(const float* __restrict__ pred,
                                                        const float* __restrict__ P,
                                                        float* __restrict__ accum) {
    const int pair = blockIdx.z;           // i*Vn + j
    const int i    = pair / Vn;
    const int j    = pair % Vn;
    const int b    = blockIdx.y;
    const int p    = blockIdx.x * blockDim.x + threadIdx.x;

    const float* Pm = P + ((b * Vn + i) * Vn + j) * 16;
    // Uniform across block -> scalar-cached loads.
    const float P00 = Pm[0],  P01 = Pm[1],  P02 = Pm[2],  P03 = Pm[3];
    const float P10 = Pm[4],  P11 = Pm[5],  P12 = Pm[6],  P13 = Pm[7];
    const float P20 = Pm[8],  P21 = Pm[9],  P22 = Pm[10], P23 = Pm[11];
    const float P30 = Pm[12], P31 = Pm[13], P32 = Pm[14], P33 = Pm[15];

    float num = 0.0f, den = 0.0f;

    if (p < Nn) {
        const float d = pred[(b * Vn + i) * Nn + p];
        const float x = (float)(p % Wn);
        const float y = (float)(p / Wn);

        // proj = P * (x*d, y*d, d, 1)
        const float px = fmaf(d, fmaf(P00, x, fmaf(P01, y, P02)), P03);
        const float py = fmaf(d, fmaf(P10, x, fmaf(P11, y, P12)), P13);
        const float pz = fmaf(d, fmaf(P20, x, fmaf(P21, y, P22)), P23);
        const float pw = fmaf(d, fmaf(P30, x, fmaf(P31, y, P32)), P33);

        const float invw = 1.0f / pw;
        const float X = px * invw;
        const float Y = py * invw;
        const float Z = pz * invw;   // projected depth

        const float gx = X / ((float)(Wn - 1) / 2.0f) - 1.0f;
        const float gy = Y / ((float)(Hn - 1) / 2.0f) - 1.0f;

        const bool inb = (gx >= -1.0f) & (gx <= 1.0f) & (gy >= -1.0f) & (gy <= 1.0f);
        if (inb) {
            // align_corners=False bilinear, zero padding
            const float ix = ((gx + 1.0f) * (float)Wn - 1.0f) * 0.5f;
            const float iy = ((gy + 1.0f) * (float)Hn - 1.0f) * 0.5f;
            const float x0f = floorf(ix);
            const float y0f = floorf(iy);
            const float wx1 = ix - x0f;
            const float wy1 = iy - y0f;
            const float wx0 = 1.0f - wx1;
            const float wy0 = 1.0f - wy1;
            const int x0 = (int)x0f;
            const int y0 = (int)y0f;
            const int x1 = x0 + 1;
            const int y1 = y0 + 1;

            const float* __restrict__ img = pred + (size_t)(b * Vn + j) * Nn;

            const bool vx0 = (x0 >= 0) & (x0 < Wn);
            const bool vx1 = (x1 >= 0) & (x1 < Wn);
            const bool vy0 = (y0 >= 0) & (y0 < Hn);
            const bool vy1 = (y1 >= 0) & (y1 < Hn);
            const int cx0 = min(max(x0, 0), Wn - 1);
            const int cx1 = min(max(x1, 0), Wn - 1);
            const int cy0 = min(max(y0, 0), Hn - 1);
            const int cy1 = min(max(y1, 0), Hn - 1);

            const float c00 = (vx0 & vy0) ? img[cy0 * Wn + cx0] : 0.0f;
            const float c10 = (vx1 & vy0) ? img[cy0 * Wn + cx1] : 0.0f;
            const float c01 = (vx0 & vy1) ? img[cy1 * Wn + cx0] : 0.0f;
            const float c11 = (vx1 & vy1) ? img[cy1 * Wn + cx1] : 0.0f;

            const float warped = wy0 * (wx0 * c00 + wx1 * c10) + wy1 * (wx0 * c01 + wx1 * c11);
            num = fabsf(warped - Z);
            den = 1.0f;
        }
    }

    // wave-64 shuffle reduction
    #pragma unroll
    for (int off = 32; off > 0; off >>= 1) {
        num += __shfl_down(num, off, 64);
        den += __shfl_down(den, off, 64);
    }
    __shared__ float s_num[4];
    __shared__ float s_den[4];
    const int lane = threadIdx.x & 63;
    const int wid  = threadIdx.x >> 6;
    if (lane == 0) { s_num[wid] = num; s_den[wid] = den; }
    __syncthreads();
    if (threadIdx.x == 0) {
        float n = s_num[0] + s_num[1] + s_num[2] + s_num[3];
        float dd = s_den[0] + s_den[1] + s_den[2] + s_den[3];
        atomicAdd(&accum[pair * 2 + 0], n);
        atomicAdd(&accum[pair * 2 + 1], dd);
    }
}

// ---------- Stage 3: total = sum_ij num/max(den,1) ----------
__global__ void finalize_kernel(const float* __restrict__ accum, float* __restrict__ out) {
    if (threadIdx.x == 0 && blockIdx.x == 0) {
        float t = 0.0f;
        for (int pr = 0; pr < Vn * Vn; ++pr) {
            t += accum[pr * 2 + 0] / fmaxf(accum[pr * 2 + 1], 1.0f);
        }
        out[0] = t;
    }
}

extern "C" void kernel_launch(void* const* d_in, const int* in_sizes, int n_in,
                              void* d_out, int out_size, void* d_ws, size_t ws_size,
                              hipStream_t stream) {
    const float* pred = (const float*)d_in[0];   // (B,V,H,W)
    const float* K    = (const float*)d_in[1];   // (B,4,4)
    const float* RT   = (const float*)d_in[2];   // (B,V,4,4)
    float* out = (float*)d_out;

    float* accum = (float*)d_ws;                 // 18 floats used (num,den per pair)
    float* P     = accum + 32;                   // B*V*V*16 = 1152 floats

    hipMemsetAsync(accum, 0, 32 * sizeof(float), stream);
    compute_P_kernel<<<1, 128, 0, stream>>>(K, RT, P);

    dim3 grid(Nn / 256, Bn, Vn * Vn);
    loss_main_kernel<<<grid, 256, 0, stream>>>(pred, P, accum);

    finalize_kernel<<<1, 64, 0, stream>>>(accum, out);
}

// Round 3
// 191.643 us; speedup vs baseline: 11.6418x; 11.6418x over previous
//
#include <hip/hip_runtime.h>

#define Bn 8
#define Vn 3
#define Hn 512
#define Wn 640
#define Nn (Hn * Wn)
#define PX 4      // pixels per thread (contiguous; 640 % 4 == 0 so no row wrap)
#define TPB 256

// ---------- 4x4 helpers (row-major float[16]) ----------
__device__ __forceinline__ void mat4_inv(const float* m, float* o) {
    float inv[16];
    inv[0]  =  m[5]*m[10]*m[15] - m[5]*m[11]*m[14] - m[9]*m[6]*m[15] + m[9]*m[7]*m[14] + m[13]*m[6]*m[11] - m[13]*m[7]*m[10];
    inv[4]  = -m[4]*m[10]*m[15] + m[4]*m[11]*m[14] + m[8]*m[6]*m[15] - m[8]*m[7]*m[14] - m[12]*m[6]*m[11] + m[12]*m[7]*m[10];
    inv[8]  =  m[4]*m[9]*m[15]  - m[4]*m[11]*m[13] - m[8]*m[5]*m[15] + m[8]*m[7]*m[13] + m[12]*m[5]*m[11] - m[12]*m[7]*m[9];
    inv[12] = -m[4]*m[9]*m[14]  + m[4]*m[10]*m[13] + m[8]*m[5]*m[14] - m[8]*m[6]*m[13] - m[12]*m[5]*m[10] + m[12]*m[6]*m[9];
    inv[1]  = -m[1]*m[10]*m[15] + m[1]*m[11]*m[14] + m[9]*m[2]*m[15] - m[9]*m[3]*m[14] - m[13]*m[2]*m[11] + m[13]*m[3]*m[10];
    inv[5]  =  m[0]*m[10]*m[15] - m[0]*m[11]*m[14] - m[8]*m[2]*m[15] + m[8]*m[3]*m[14] + m[12]*m[2]*m[11] - m[12]*m[3]*m[10];
    inv[9]  = -m[0]*m[9]*m[15]  + m[0]*m[11]*m[13] + m[8]*m[1]*m[15] - m[8]*m[3]*m[13] - m[12]*m[1]*m[11] + m[12]*m[3]*m[9];
    inv[13] =  m[0]*m[9]*m[14]  - m[0]*m[10]*m[13] - m[8]*m[1]*m[14] + m[8]*m[2]*m[13] + m[12]*m[1]*m[10] - m[12]*m[2]*m[9];
    inv[2]  =  m[1]*m[6]*m[15]  - m[1]*m[7]*m[14]  - m[5]*m[2]*m[15] + m[5]*m[3]*m[14] + m[13]*m[2]*m[7]  - m[13]*m[3]*m[6];
    inv[6]  = -m[0]*m[6]*m[15]  + m[0]*m[7]*m[14]  + m[4]*m[2]*m[15] - m[4]*m[3]*m[14] - m[12]*m[2]*m[7]  + m[12]*m[3]*m[6];
    inv[10] =  m[0]*m[5]*m[15]  - m[0]*m[7]*m[13]  - m[4]*m[1]*m[15] + m[4]*m[3]*m[13] + m[12]*m[1]*m[7]  - m[12]*m[3]*m[5];
    inv[14] = -m[0]*m[5]*m[14]  + m[0]*m[6]*m[13]  + m[4]*m[1]*m[14] - m[4]*m[2]*m[13] - m[12]*m[1]*m[6]  + m[12]*m[2]*m[5];
    inv[3]  = -m[1]*m[6]*m[11]  + m[1]*m[7]*m[10]  + m[5]*m[2]*m[11] - m[5]*m[3]*m[10] - m[9]*m[2]*m[7]   + m[9]*m[3]*m[6];
    inv[7]  =  m[0]*m[6]*m[11]  - m[0]*m[7]*m[10]  - m[4]*m[2]*m[11] + m[4]*m[3]*m[10] + m[8]*m[2]*m[7]   - m[8]*m[3]*m[6];
    inv[11] = -m[0]*m[5]*m[11]  + m[0]*m[7]*m[9]   + m[4]*m[1]*m[11] - m[4]*m[3]*m[9]  - m[8]*m[1]*m[7]   + m[8]*m[3]*m[5];
    inv[15] =  m[0]*m[5]*m[10]  - m[0]*m[6]*m[9]   - m[4]*m[1]*m[10] + m[4]*m[2]*m[9]  + m[8]*m[1]*m[6]   - m[8]*m[2]*m[5];
    float det = m[0]*inv[0] + m[1]*inv[4] + m[2]*inv[8] + m[3]*inv[12];
    float rdet = 1.0f / det;
    for (int k = 0; k < 16; ++k) o[k] = inv[k] * rdet;
}

__device__ __forceinline__ void mat4_mul(const float* a, const float* b, float* c) {
    for (int r = 0; r < 4; ++r)
        for (int col = 0; col < 4; ++col) {
            float s = 0.0f;
            for (int k = 0; k < 4; ++k) s = fmaf(a[r*4 + k], b[k*4 + col], s);
            c[r*4 + col] = s;
        }
}

// ---------- Stage 1: P[b,i,j] = K[b] * RT[b,j] * inv(RT[b,i]) * inv(K[b]) ----------
__global__ void compute_P_kernel(const float* __restrict__ K,
                                 const float* __restrict__ RT,
                                 float* __restrict__ P) {
    int idx = blockIdx.x * blockDim.x + threadIdx.x;
    if (idx >= Bn * Vn * Vn) return;
    int b  = idx / (Vn * Vn);
    int ij = idx % (Vn * Vn);
    int i  = ij / Vn;
    int j  = ij % Vn;

    float Kb[16], Kinv[16], RTj[16], RTi[16], RTiinv[16], t1[16], t2[16], Pm[16];
    for (int k = 0; k < 16; ++k) Kb[k]  = K[b * 16 + k];
    for (int k = 0; k < 16; ++k) RTj[k] = RT[(b * Vn + j) * 16 + k];
    for (int k = 0; k < 16; ++k) RTi[k] = RT[(b * Vn + i) * 16 + k];
    mat4_inv(Kb, Kinv);
    mat4_inv(RTi, RTiinv);
    mat4_mul(Kb, RTj, t1);
    mat4_mul(t1, RTiinv, t2);
    mat4_mul(t2, Kinv, Pm);
    for (int k = 0; k < 16; ++k) P[idx * 16 + k] = Pm[k];
}

// ---------- Stage 2: 4 px/thread, ALL 3 j's per i in one pass ----------
__global__ __launch_bounds__(TPB) void loss_main_kernel(const float* __restrict__ pred,
                                                        const float* __restrict__ P,
                                                        float* __restrict__ accum) {
    const int i = blockIdx.z;            // source view
    const int b = blockIdx.y;

    const int base = (blockIdx.x * TPB + threadIdx.x) * PX;
    const int yrow = base / Wn;          // PX=4 divides 640 -> no row wrap within a thread
    const int xcol = base - yrow * Wn;
    const float fy = (float)yrow;

    const float4 d4 = *reinterpret_cast<const float4*>(pred + (size_t)(b * Vn + i) * Nn + base);
    const float dv[PX] = {d4.x, d4.y, d4.z, d4.w};

    float num[Vn] = {0.0f, 0.0f, 0.0f};
    float den[Vn] = {0.0f, 0.0f, 0.0f};

    #pragma unroll
    for (int j = 0; j < Vn; ++j) {
        const float* Pm = P + (size_t)((b * Vn + i) * Vn + j) * 16;
        const float P00 = Pm[0],  P01 = Pm[1],  P02 = Pm[2],  P03 = Pm[3];
        const float P10 = Pm[4],  P11 = Pm[5],  P12 = Pm[6],  P13 = Pm[7];
        const float P20 = Pm[8],  P21 = Pm[9],  P22 = Pm[10], P23 = Pm[11];
        const float P30 = Pm[12], P31 = Pm[13], P32 = Pm[14], P33 = Pm[15];
        const float* __restrict__ img = pred + (size_t)(b * Vn + j) * Nn;

        #pragma unroll
        for (int k = 0; k < PX; ++k) {
            const float d  = dv[k];
            const float fx = (float)(xcol + k);

            // proj = P * (x*d, y*d, d, 1); reference divides by proj[3] (w), NOT depth.
            const float px = fmaf(d, fmaf(P00, fx, fmaf(P01, fy, P02)), P03);
            const float py = fmaf(d, fmaf(P10, fx, fmaf(P11, fy, P12)), P13);
            const float pz = fmaf(d, fmaf(P20, fx, fmaf(P21, fy, P22)), P23);
            const float pw = fmaf(d, fmaf(P30, fx, fmaf(P31, fy, P32)), P33);

            const float invw = 1.0f / pw;
            const float X = px * invw;
            const float Y = py * invw;
            const float Z = pz * invw;   // projected depth

            const float gx = X / ((float)(Wn - 1) / 2.0f) - 1.0f;
            const float gy = Y / ((float)(Hn - 1) / 2.0f) - 1.0f;

            const bool inb = (gx >= -1.0f) & (gx <= 1.0f) & (gy >= -1.0f) & (gy <= 1.0f);
            if (inb) {
                const float ix = ((gx + 1.0f) * (float)Wn - 1.0f) * 0.5f;
                const float iy = ((gy + 1.0f) * (float)Hn - 1.0f) * 0.5f;
                const float x0f = floorf(ix);
                const float y0f = floorf(iy);
                const float wx1 = ix - x0f;
                const float wy1 = iy - y0f;
                const float wx0 = 1.0f - wx1;
                const float wy0 = 1.0f - wy1;
                const int x0 = (int)x0f;
                const int y0 = (int)y0f;
                const int x1 = x0 + 1;
                const int y1 = y0 + 1;

                const bool vx0 = (x0 >= 0) & (x0 < Wn);
                const bool vx1 = (x1 >= 0) & (x1 < Wn);
                const bool vy0 = (y0 >= 0) & (y0 < Hn);
                const bool vy1 = (y1 >= 0) & (y1 < Hn);
                const int cx0 = min(max(x0, 0), Wn - 1);
                const int cx1 = min(max(x1, 0), Wn - 1);
                const int cy0 = min(max(y0, 0), Hn - 1);
                const int cy1 = min(max(y1, 0), Hn - 1);

                const float c00 = (vx0 & vy0) ? img[cy0 * Wn + cx0] : 0.0f;
                const float c10 = (vx1 & vy0) ? img[cy0 * Wn + cx1] : 0.0f;
                const float c01 = (vx0 & vy1) ? img[cy1 * Wn + cx0] : 0.0f;
                const float c11 = (vx1 & vy1) ? img[cy1 * Wn + cx1] : 0.0f;

                const float warped = wy0 * (wx0 * c00 + wx1 * c10) + wy1 * (wx0 * c01 + wx1 * c11);
                num[j] += fabsf(warped - Z);
                den[j] += 1.0f;
            }
        }
    }

    // wave-64 shuffle reduction over 6 independent accumulators
    #pragma unroll
    for (int off = 32; off > 0; off >>= 1) {
        #pragma unroll
        for (int j = 0; j < Vn; ++j) {
            num[j] += __shfl_down(num[j], off, 64);
            den[j] += __shfl_down(den[j], off, 64);
        }
    }
    __shared__ float s_red[4][2 * Vn];   // [wave][n0,d0,n1,d1,n2,d2]
    const int lane = threadIdx.x & 63;
    const int wid  = threadIdx.x >> 6;
    if (lane == 0) {
        #pragma unroll
        for (int j = 0; j < Vn; ++j) {
            s_red[wid][2 * j + 0] = num[j];
            s_red[wid][2 * j + 1] = den[j];
        }
    }
    __syncthreads();
    if (threadIdx.x < 2 * Vn) {
        const int slot = threadIdx.x;       // 0..5 -> (pair accumulator component)
        float v = s_red[0][slot] + s_red[1][slot] + s_red[2][slot] + s_red[3][slot];
        const int j = slot >> 1;
        const int comp = slot & 1;
        atomicAdd(&accum[(i * Vn + j) * 2 + comp], v);
    }
}

// ---------- Stage 3: total = sum_ij num/max(den,1) ----------
__global__ void finalize_kernel(const float* __restrict__ accum, float* __restrict__ out) {
    if (threadIdx.x == 0 && blockIdx.x == 0) {
        float t = 0.0f;
        for (int pr = 0; pr < Vn * Vn; ++pr) {
            t += accum[pr * 2 + 0] / fmaxf(accum[pr * 2 + 1], 1.0f);
        }
        out[0] = t;
    }
}

extern "C" void kernel_launch(void* const* d_in, const int* in_sizes, int n_in,
                              void* d_out, int out_size, void* d_ws, size_t ws_size,
                              hipStream_t stream) {
    const float* pred = (const float*)d_in[0];   // (B,V,H,W)
    const float* K    = (const float*)d_in[1];   // (B,4,4)
    const float* RT   = (const float*)d_in[2];   // (B,V,4,4)
    float* out = (float*)d_out;

    float* accum = (float*)d_ws;                 // 18 floats used (num,den per pair)
    float* P     = accum + 32;                   // B*V*V*16 = 1152 floats

    hipMemsetAsync(accum, 0, 32 * sizeof(float), stream);
    compute_P_kernel<<<1, 128, 0, stream>>>(K, RT, P);

    dim3 grid(Nn / (TPB * PX), Bn, Vn);          // 320 x 8 x 3
    loss_main_kernel<<<grid, TPB, 0, stream>>>(pred, P, accum);

    finalize_kernel<<<1, 64, 0, stream>>>(accum, out);
}

// Round 4
// 190.065 us; speedup vs baseline: 11.7385x; 1.0083x over previous
//
#include <hip/hip_runtime.h>

#define Bn 8
#define Vn 3
#define Hn 512
#define Wn 640
#define Nn (Hn * Wn)
#define PX 8                      // pixels per thread (8 divides 640: no row wrap)
#define TPB 256
#define XBLKS (Nn / (TPB * PX))   // 160
#define GRIDN (XBLKS * Vn * Bn)   // 3840 blocks

// ---------- 4x4 helpers (row-major float[16]) ----------
__device__ __forceinline__ void mat4_inv(const float* m, float* o) {
    float inv[16];
    inv[0]  =  m[5]*m[10]*m[15] - m[5]*m[11]*m[14] - m[9]*m[6]*m[15] + m[9]*m[7]*m[14] + m[13]*m[6]*m[11] - m[13]*m[7]*m[10];
    inv[4]  = -m[4]*m[10]*m[15] + m[4]*m[11]*m[14] + m[8]*m[6]*m[15] - m[8]*m[7]*m[14] - m[12]*m[6]*m[11] + m[12]*m[7]*m[10];
    inv[8]  =  m[4]*m[9]*m[15]  - m[4]*m[11]*m[13] - m[8]*m[5]*m[15] + m[8]*m[7]*m[13] + m[12]*m[5]*m[11] - m[12]*m[7]*m[9];
    inv[12] = -m[4]*m[9]*m[14]  + m[4]*m[10]*m[13] + m[8]*m[5]*m[14] - m[8]*m[6]*m[13] - m[12]*m[5]*m[10] + m[12]*m[6]*m[9];
    inv[1]  = -m[1]*m[10]*m[15] + m[1]*m[11]*m[14] + m[9]*m[2]*m[15] - m[9]*m[3]*m[14] - m[13]*m[2]*m[11] + m[13]*m[3]*m[10];
    inv[5]  =  m[0]*m[10]*m[15] - m[0]*m[11]*m[14] - m[8]*m[2]*m[15] + m[8]*m[3]*m[14] + m[12]*m[2]*m[11] - m[12]*m[3]*m[10];
    inv[9]  = -m[0]*m[9]*m[15]  + m[0]*m[11]*m[13] + m[8]*m[1]*m[15] - m[8]*m[3]*m[13] - m[12]*m[1]*m[11] + m[12]*m[3]*m[9];
    inv[13] =  m[0]*m[9]*m[14]  - m[0]*m[10]*m[13] - m[8]*m[1]*m[14] + m[8]*m[2]*m[13] + m[12]*m[1]*m[10] - m[12]*m[2]*m[9];
    inv[2]  =  m[1]*m[6]*m[15]  - m[1]*m[7]*m[14]  - m[5]*m[2]*m[15] + m[5]*m[3]*m[14] + m[13]*m[2]*m[7]  - m[13]*m[3]*m[6];
    inv[6]  = -m[0]*m[6]*m[15]  + m[0]*m[7]*m[14]  + m[4]*m[2]*m[15] - m[4]*m[3]*m[14] - m[12]*m[2]*m[7]  + m[12]*m[3]*m[6];
    inv[10] =  m[0]*m[5]*m[15]  - m[0]*m[7]*m[13]  - m[4]*m[1]*m[15] + m[4]*m[3]*m[13] + m[12]*m[1]*m[7]  - m[12]*m[3]*m[5];
    inv[14] = -m[0]*m[5]*m[14]  + m[0]*m[6]*m[13]  + m[4]*m[1]*m[14] - m[4]*m[2]*m[13] - m[12]*m[1]*m[6]  + m[12]*m[2]*m[5];
    inv[3]  = -m[1]*m[6]*m[11]  + m[1]*m[7]*m[10]  + m[5]*m[2]*m[11] - m[5]*m[3]*m[10] - m[9]*m[2]*m[7]   + m[9]*m[3]*m[6];
    inv[7]  =  m[0]*m[6]*m[11]  - m[0]*m[7]*m[10]  - m[4]*m[2]*m[11] + m[4]*m[3]*m[10] + m[8]*m[2]*m[7]   - m[8]*m[3]*m[6];
    inv[11] = -m[0]*m[5]*m[11]  + m[0]*m[7]*m[9]   + m[4]*m[1]*m[11] - m[4]*m[3]*m[9]  - m[8]*m[1]*m[7]   + m[8]*m[3]*m[5];
    inv[15] =  m[0]*m[5]*m[10]  - m[0]*m[6]*m[9]   - m[4]*m[1]*m[10] + m[4]*m[2]*m[9]  + m[8]*m[1]*m[6]   - m[8]*m[2]*m[5];
    float det = m[0]*inv[0] + m[1]*inv[4] + m[2]*inv[8] + m[3]*inv[12];
    float rdet = 1.0f / det;
    for (int k = 0; k < 16; ++k) o[k] = inv[k] * rdet;
}

__device__ __forceinline__ void mat4_mul(const float* a, const float* b, float* c) {
    for (int r = 0; r < 4; ++r)
        for (int col = 0; col < 4; ++col) {
            float s = 0.0f;
            for (int k = 0; k < 4; ++k) s = fmaf(a[r*4 + k], b[k*4 + col], s);
            c[r*4 + col] = s;
        }
}

// ---------- Stage 1: P[b,i,j] = K[b] * RT[b,j] * inv(RT[b,i]) * inv(K[b]) ----------
__global__ void compute_P_kernel(const float* __restrict__ K,
                                 const float* __restrict__ RT,
                                 float* __restrict__ P) {
    int idx = blockIdx.x * blockDim.x + threadIdx.x;
    if (idx >= Bn * Vn * Vn) return;
    int b  = idx / (Vn * Vn);
    int ij = idx % (Vn * Vn);
    int i  = ij / Vn;
    int j  = ij % Vn;

    float Kb[16], Kinv[16], RTj[16], RTi[16], RTiinv[16], t1[16], t2[16], Pm[16];
    for (int k = 0; k < 16; ++k) Kb[k]  = K[b * 16 + k];
    for (int k = 0; k < 16; ++k) RTj[k] = RT[(b * Vn + j) * 16 + k];
    for (int k = 0; k < 16; ++k) RTi[k] = RT[(b * Vn + i) * 16 + k];
    mat4_inv(Kb, Kinv);
    mat4_inv(RTi, RTiinv);
    mat4_mul(Kb, RTj, t1);
    mat4_mul(t1, RTiinv, t2);
    mat4_mul(t2, Kinv, Pm);
    for (int k = 0; k < 16; ++k) P[idx * 16 + k] = Pm[k];
}

// ---------- Stage 2: 8 px/thread, all 3 j per i, XCD-batch swizzle, fused finalize ----
__global__ __launch_bounds__(TPB) void loss_main_kernel(const float* __restrict__ pred,
                                                        const float* __restrict__ P,
                                                        float* __restrict__ accum,
                                                        unsigned* __restrict__ counter,
                                                        float* __restrict__ out) {
    // b = blockIdx.x % 8: consecutive workgroups round-robin over the 8 XCDs,
    // so each XCD's 4 MB L2 holds exactly one batch's 3 planes (3.93 MB).
    const int idx  = blockIdx.x;
    const int b    = idx & 7;
    const int r    = idx >> 3;
    const int i    = r % Vn;
    const int xblk = r / Vn;

    const int base = (xblk * TPB + threadIdx.x) * PX;
    const int yrow = base / Wn;
    const int xcol = base - yrow * Wn;
    const float fy = (float)yrow;

    const float* dptr = pred + (size_t)(b * Vn + i) * Nn + base;
    float dv[PX];
    {
        const float4 a0 = *reinterpret_cast<const float4*>(dptr);
        const float4 a1 = *reinterpret_cast<const float4*>(dptr + 4);
        dv[0] = a0.x; dv[1] = a0.y; dv[2] = a0.z; dv[3] = a0.w;
        dv[4] = a1.x; dv[5] = a1.y; dv[6] = a1.z; dv[7] = a1.w;
    }

    const float cW = (float)Wn / (float)(Wn - 1);   // ix = X*cW - 0.5
    const float cH = (float)Hn / (float)(Hn - 1);

    float num[Vn] = {0.0f, 0.0f, 0.0f};
    float den[Vn] = {0.0f, 0.0f, 0.0f};

    #pragma unroll
    for (int j = 0; j < Vn; ++j) {
        const float* Pm = P + (size_t)((b * Vn + i) * Vn + j) * 16;   // block-uniform -> s_load
        const float P00 = Pm[0],  P01 = Pm[1],  P02 = Pm[2],  P03 = Pm[3];
        const float P10 = Pm[4],  P11 = Pm[5],  P12 = Pm[6],  P13 = Pm[7];
        const float P20 = Pm[8],  P21 = Pm[9],  P22 = Pm[10], P23 = Pm[11];
        const float P30 = Pm[12], P31 = Pm[13], P32 = Pm[14], P33 = Pm[15];
        const float* __restrict__ img = pred + (size_t)(b * Vn + j) * Nn;

        #pragma unroll
        for (int k = 0; k < PX; ++k) {
            const float d  = dv[k];
            const float fx = (float)(xcol + k);

            // proj = P * (x*d, y*d, d, 1); divide by w (proj[3]).
            const float px = fmaf(d, fmaf(P00, fx, fmaf(P01, fy, P02)), P03);
            const float py = fmaf(d, fmaf(P10, fx, fmaf(P11, fy, P12)), P13);
            const float pz = fmaf(d, fmaf(P20, fx, fmaf(P21, fy, P22)), P23);
            const float pw = fmaf(d, fmaf(P30, fx, fmaf(P31, fy, P32)), P33);

            const float invw = 1.0f / pw;
            const float X = px * invw;
            const float Y = py * invw;
            const float Z = pz * invw;   // projected depth

            // gx in [-1,1]  <=>  X in [0, W-1]  (same for Y)
            const bool inb = (X >= 0.0f) & (X <= (float)(Wn - 1)) &
                             (Y >= 0.0f) & (Y <= (float)(Hn - 1));
            if (inb) {
                const float ix = fmaf(X, cW, -0.5f);
                const float iy = fmaf(Y, cH, -0.5f);
                const float x0f = floorf(ix);
                const float y0f = floorf(iy);
                const float wx1 = ix - x0f;
                const float wy1 = iy - y0f;
                const float wx0 = 1.0f - wx1;
                const float wy0 = 1.0f - wy1;
                const int x0 = (int)x0f;           // in [-1, W-1]
                const int y0 = (int)y0f;           // in [-1, H-1]
                const int x1 = x0 + 1;             // in [0, W]
                const int y1 = y0 + 1;             // in [0, H]
                const int cx0 = max(x0, 0);
                const int cx1 = min(x1, Wn - 1);
                const int cy0 = max(y0, 0);
                const int cy1 = min(y1, Hn - 1);

                const float c00 = img[cy0 * Wn + cx0];
                const float c10 = img[cy0 * Wn + cx1];
                const float c01 = img[cy1 * Wn + cx0];
                const float c11 = img[cy1 * Wn + cx1];

                // zero-padding: mask the weights (values are finite positives)
                const float wx0v = (x0 >= 0) ? wx0 : 0.0f;
                const float wx1v = (x1 <  Wn) ? wx1 : 0.0f;
                const float wy0v = (y0 >= 0) ? wy0 : 0.0f;
                const float wy1v = (y1 <  Hn) ? wy1 : 0.0f;

                const float warped = wy0v * fmaf(wx0v, c00, wx1v * c10)
                                   + wy1v * fmaf(wx0v, c01, wx1v * c11);
                num[j] += fabsf(warped - Z);
                den[j] += 1.0f;
            }
        }
    }

    // wave-64 shuffle reduction over 6 independent accumulators
    #pragma unroll
    for (int off = 32; off > 0; off >>= 1) {
        #pragma unroll
        for (int j = 0; j < Vn; ++j) {
            num[j] += __shfl_down(num[j], off, 64);
            den[j] += __shfl_down(den[j], off, 64);
        }
    }
    __shared__ float s_red[4][2 * Vn];
    __shared__ int s_last;
    const int lane = threadIdx.x & 63;
    const int wid  = threadIdx.x >> 6;
    if (lane == 0) {
        #pragma unroll
        for (int j = 0; j < Vn; ++j) {
            s_red[wid][2 * j + 0] = num[j];
            s_red[wid][2 * j + 1] = den[j];
        }
    }
    __syncthreads();
    if (threadIdx.x < 2 * Vn) {
        const int slot = threadIdx.x;
        float v = s_red[0][slot] + s_red[1][slot] + s_red[2][slot] + s_red[3][slot];
        const int j = slot >> 1;
        const int comp = slot & 1;
        atomicAdd(&accum[(i * Vn + j) * 2 + comp], v);
    }
    // make this block's atomics globally visible, then take a ticket
    __syncthreads();
    if (threadIdx.x == 0) {
        __threadfence();
        unsigned old = atomicAdd(counter, 1u);
        s_last = (old == (unsigned)(GRIDN - 1)) ? 1 : 0;
    }
    __syncthreads();
    if (s_last && threadIdx.x == 0) {
        float t = 0.0f;
        for (int pr = 0; pr < Vn * Vn; ++pr) {
            // read through atomics (coherence point) to avoid stale cache reads
            float n  = atomicAdd(&accum[pr * 2 + 0], 0.0f);
            float dd = atomicAdd(&accum[pr * 2 + 1], 0.0f);
            t += n / fmaxf(dd, 1.0f);
        }
        out[0] = t;
    }
}

extern "C" void kernel_launch(void* const* d_in, const int* in_sizes, int n_in,
                              void* d_out, int out_size, void* d_ws, size_t ws_size,
                              hipStream_t stream) {
    const float* pred = (const float*)d_in[0];   // (B,V,H,W)
    const float* K    = (const float*)d_in[1];   // (B,4,4)
    const float* RT   = (const float*)d_in[2];   // (B,V,4,4)
    float* out = (float*)d_out;

    float*    accum   = (float*)d_ws;            // 18 floats (num,den per pair)
    unsigned* counter = (unsigned*)d_ws + 24;    // done-block counter
    float*    P       = (float*)d_ws + 32;       // B*V*V*16 = 1152 floats

    hipMemsetAsync(d_ws, 0, 128, stream);        // zeroes accum + counter
    compute_P_kernel<<<1, 128, 0, stream>>>(K, RT, P);
    loss_main_kernel<<<GRIDN, TPB, 0, stream>>>(pred, P, accum, counter, out);
}